// Round 12
// baseline (140.395 us; speedup 1.0000x reference)
//
#include <hip/hip_runtime.h>
#include <hip/hip_bf16.h>

// Decoder loss: keep-mask (kth-value threshold + local max), BCE coord loss,
// bidirectional NN recolor + L1 rgb loss.
// L=16384 candidates, N=10000 targets, K=8 (collapses to argmin; R1-proven).
// R18 (resubmit; R11 bench was a broker GPUAcquisitionTimeout, no data):
// R14 base (132.1/132.4/132.6, thrice-proven) + packed-FP32 inner loop.
// gfx950 has v_pk_fma_f32 (VOP3P): pair the 4 j-outputs into <2 x float>
// lanes -> 12 scalar fma/c-step become 6 pk_fma. cmp/select stay scalar
// (exact d<best first-min tie-break preserved; pk_fma is IEEE fma per half).
// DIAGNOSTIC round: VALUBusy 56->~42% + dur 43->35 => issue-limited;
// VALUBusy drops + dur flat => latency-limited (structural ceiling proven);
// VALUBusy flat => builtins didn't lower to VOP3P.
// Hard-learned rules for this part:
//   - scan loop: 0.165+-0.005 cyc/pair across SIX configs (R8-R16): invariant
//     to VALU count, LDS ratio, occupancy, split/concurrent at HIP level.
//   - R15: per-thread grid/shell NN = latency-serialized divergent gather
//     (439us, VALUBusy 0.75%). NEVER pointer-chase NN per-thread here.
//   - scan needs >=128 c-steps per barrier pair (R13: 32-step = 62us) and
//     dual-grid concurrency (R16: serializing bwd/fwd lost 7us).
//   - kernel boundaries ~free (R14); grid.sync ~40us (R4); mass threadfence
//     ~0.1ms (R7). 17-block co-resident release/acquire handshakes OK.
//   - per-chunk surrogate argmin + cross-chunk EXACT-d merge key (R1/R3).
//   - budget ledger (R16): 132 = 40us harness 256MiB re-poison fill (not
//     controllable) + ~70us my kernels + ~20us launch floor.

#define SCAN_T 256   // threads per block (scan)
#define CHUNK  128   // tile elements per y-chunk
typedef unsigned long long ull;
typedef float f2 __attribute__((ext_vector_type(2)));

// ---- helper: pick bin containing rank from LDS hist (wave 0) ---------------
__device__ __forceinline__ void select_bin(
    unsigned int* hist, int nb, unsigned int rank,
    unsigned int* sB, unsigned int* sR, int tid) {
  if (tid < 64) {
    int g = nb >> 6;
    unsigned int sum = 0;
    for (int j = 0; j < g; ++j) sum += hist[tid * g + j];
    unsigned int incl = sum;
    for (int o = 1; o < 64; o <<= 1) {
      unsigned int v = __shfl_up(incl, o);
      if (tid >= o) incl += v;
    }
    unsigned int excl = incl - sum;
    bool cond = (rank >= excl) && (rank < incl);
    unsigned long long bal = __ballot(cond);
    int first = __ffsll((long long)bal) - 1;
    if (tid == first) {
      unsigned int r = rank - excl, cum = 0;
      for (int j = 0; j < g; ++j) {
        unsigned int c = hist[tid * g + j];
        if (r < cum + c) { *sB = (unsigned int)(tid * g + j); *sR = r - cum; break; }
        cum += c;
      }
    }
  }
}

// ---- Kernel 1: fused init + keys + select + keep/compact/BCE ---------------
// Blocks 0..IB-1: array init, then acquire-spin on counters[15], then the
// old k_keepc role (keep mask, klist compaction, BCE reduce).
// Block IB (selector): monotone keys into LDS + islm, 3-sweep radix select,
// writes thr + zeroes accumulators, release-stores counters[15]=1.
// All IB+1 = 17 blocks co-resident (<= 256 CUs) -> no deadlock; selector
// never waits on init blocks. AGENT-scope atomics for cross-XCD visibility.
__global__ __launch_bounds__(1024) void k_init_sel(
    const float* __restrict__ pred, const float* __restrict__ txyz,
    const float* __restrict__ cxyz, const int* __restrict__ ktgt,
    const int* __restrict__ pnum_p,
    float4* __restrict__ ttile, float4* __restrict__ numden,
    int* __restrict__ zerohit, ull* __restrict__ tmin, ull* __restrict__ fmin,
    unsigned char* __restrict__ islm, int* __restrict__ keep,
    float4* __restrict__ klist, int* __restrict__ kidx,
    int* counters, float* __restrict__ out, float* __restrict__ thr_out,
    int L, int N, int IB) {
  __shared__ unsigned int skey[16384];
  __shared__ unsigned int hist[2048];
  __shared__ unsigned int sB, sR;
  __shared__ float s_thr;
  int tid = threadIdx.x;

  if ((int)blockIdx.x < IB) {
    // ---- init role --------------------------------------------------------
    int gidx = blockIdx.x * 1024 + tid;
    int gsz = IB * 1024;
    for (int i = gidx; i < N; i += gsz) {
      float x = txyz[3*i], y = txyz[3*i+1], z = txyz[3*i+2];
      ttile[i] = make_float4(x, y, z, fmaf(x, x, fmaf(y, y, z * z)));
      tmin[i] = ~0ull;
    }
    for (int i = gidx; i < L; i += gsz) {
      numden[i] = make_float4(0.f, 0.f, 0.f, 0.f);
      zerohit[i] = 0;
      fmin[i] = ~0ull;
    }
    // ---- handshake: wait for selector's thr (release/acquire, AGENT) ------
    if (tid == 0) {
      while (__hip_atomic_load(&counters[15], __ATOMIC_ACQUIRE,
                               __HIP_MEMORY_SCOPE_AGENT) == 0)
        __builtin_amdgcn_s_sleep(8);
      s_thr = thr_out[0];
    }
    __syncthreads();
    float thr = s_thr;
    // ---- keepc role: keep mask + compaction + BCE -------------------------
    // wave = 64 consecutive i -> identical atomicAdd grouping to R12 keepc.
    float term = 0.f;
    for (int i = gidx; i < L; i += gsz) {
      float p = pred[i];
      bool kp = (p > thr) || islm[i];
      keep[i] = kp ? 1 : 0;
      if (kp) {
        int pos = atomicAdd(&counters[0], 1);   // order irrelevant (no ties)
        float x = cxyz[3*i], y = cxyz[3*i+1], z = cxyz[3*i+2];
        klist[pos] = make_float4(x, y, z, fmaf(x, x, fmaf(y, y, z * z)));
        kidx[pos] = i;
      }
      float t = (float)ktgt[i];
      term += fmaxf(p, 0.f) - p * t + log1pf(expf(-fabsf(p)));
    }
    for (int o = 32; o > 0; o >>= 1) term += __shfl_down(term, o);
    if ((tid & 63) == 0) atomicAdd(&out[0], term);
    return;
  }

  // ---- selector role ------------------------------------------------------
  // phase A: monotone keys (LDS) + per-8 local max (global islm)
  int ngroups = L >> 3;
  for (int g = tid; g < ngroups; g += 1024) {
    const float4* pv = (const float4*)pred + (size_t)g * 2;
    float4 a = pv[0], b = pv[1];
    float v[8] = {a.x, a.y, a.z, a.w, b.x, b.y, b.z, b.w};
    int bi = 0; float bv = v[0];
    #pragma unroll
    for (int j = 1; j < 8; ++j) if (v[j] > bv) { bv = v[j]; bi = j; }
    ull lmpack = 0ull;
    #pragma unroll
    for (int j = 0; j < 8; ++j) {
      unsigned int fb = __float_as_uint(v[j]);
      unsigned int mk = (fb & 0x80000000u) ? ~fb : (fb | 0x80000000u);
      if (j == bi) { mk = 0xFF800000u; lmpack |= 1ull << (8 * j); }  // +inf
      skey[g * 8 + j] = mk;
    }
    *(ull*)(islm + (size_t)g * 8) = lmpack;
  }
  __syncthreads();

  // phase B: 3-sweep radix select over LDS keys
  unsigned int rank = (unsigned int)(L - pnum_p[0] - 1);
  const uint4* s4 = (const uint4*)skey;
  int n4 = L >> 2;
  for (int b = tid; b < 2048; b += 1024) hist[b] = 0u;
  __syncthreads();
  for (int i = tid; i < n4; i += 1024) {
    uint4 v = s4[i];
    atomicAdd(&hist[v.x >> 21], 1u); atomicAdd(&hist[v.y >> 21], 1u);
    atomicAdd(&hist[v.z >> 21], 1u); atomicAdd(&hist[v.w >> 21], 1u);
  }
  __syncthreads();
  select_bin(hist, 2048, rank, &sB, &sR, tid);
  __syncthreads();
  unsigned int B1 = sB, R1 = sR;
  for (int b = tid; b < 2048; b += 1024) hist[b] = 0u;
  __syncthreads();
  for (int i = tid; i < n4; i += 1024) {
    uint4 v = s4[i];
    if ((v.x >> 21) == B1) atomicAdd(&hist[(v.x >> 10) & 2047u], 1u);
    if ((v.y >> 21) == B1) atomicAdd(&hist[(v.y >> 10) & 2047u], 1u);
    if ((v.z >> 21) == B1) atomicAdd(&hist[(v.z >> 10) & 2047u], 1u);
    if ((v.w >> 21) == B1) atomicAdd(&hist[(v.w >> 10) & 2047u], 1u);
  }
  __syncthreads();
  select_bin(hist, 2048, R1, &sB, &sR, tid);
  __syncthreads();
  unsigned int B2 = sB, R2 = sR;
  for (int b = tid; b < 1024; b += 1024) hist[b] = 0u;
  __syncthreads();
  unsigned int top22 = (B1 << 11) | B2;
  for (int i = tid; i < n4; i += 1024) {
    uint4 v = s4[i];
    if ((v.x >> 10) == top22) atomicAdd(&hist[v.x & 1023u], 1u);
    if ((v.y >> 10) == top22) atomicAdd(&hist[v.y & 1023u], 1u);
    if ((v.z >> 10) == top22) atomicAdd(&hist[v.z & 1023u], 1u);
    if ((v.w >> 10) == top22) atomicAdd(&hist[v.w & 1023u], 1u);
  }
  __syncthreads();
  select_bin(hist, 1024, R2, &sB, &sR, tid);
  __syncthreads();
  if (tid == 0) {
    unsigned int fkey = (B1 << 21) | (B2 << 10) | sB;
    unsigned int fb = (fkey & 0x80000000u) ? (fkey & 0x7FFFFFFFu) : ~fkey;
    thr_out[0] = __uint_as_float(fb);
    out[0] = 0.f; out[1] = 0.f;       // accumulators zeroed BEFORE release
    #pragma unroll
    for (int c = 0; c < 8; ++c) counters[c] = 0;
  }
  __syncthreads();   // islm + thr + zeroes happen-before the release store
  if (tid == 0)
    __hip_atomic_store(&counters[15], 1, __ATOMIC_RELEASE,
                       __HIP_MEMORY_SCOPE_AGENT);
}

// ---- Kernel 2: dual-role scan (bwd y<YB, fwd y>=YB), LDS-tiled -------------
// R10 structure (4 outputs/thread, CHUNK=128, ~1270 concurrent blocks) with
// R18 packed-FP32 inner arithmetic: j-pairs in <2 x float> -> v_pk_fma_f32.
// cmp/select scalar: exact `d < best` first-min tie-break preserved.
__global__ __launch_bounds__(SCAN_T) void k_scan2(
    const float* __restrict__ txyz, const float4* __restrict__ klist,
    const int* __restrict__ kidx, const float4* __restrict__ ttile,
    const int* __restrict__ counters, ull* __restrict__ tmin,
    ull* __restrict__ fmin, int L, int N, int YB) {
  __shared__ float4 tile[CHUNK];
  int tid = threadIdx.x, x = blockIdx.x, y = blockIdx.y;
  int kc = counters[0];

  if (y < YB) {
    // ---- backward: targets x*1024.. (4/thread) vs kept chunk y (128) ------
    int c0 = y * CHUNK;
    if (x * 1024 >= N || c0 >= kc) return;   // uniform early-exit
    int cnt = min(CHUNK, kc - c0);
    if (tid < cnt) tile[tid] = klist[c0 + tid];
    __syncthreads();
    int tb = x * 1024 + tid;
    float ntx[4], nty[4], ntz[4], best[4];
    int bpos[4];
    bool act[4];
    #pragma unroll
    for (int j = 0; j < 4; ++j) {
      int t = tb + 256 * j;
      act[j] = t < N;
      float tx = 0.f, ty = 0.f, tz = 0.f;
      if (act[j]) { tx = txyz[3*t]; ty = txyz[3*t+1]; tz = txyz[3*t+2]; }
      ntx[j] = -2.f * tx; nty[j] = -2.f * ty; ntz[j] = -2.f * tz;
      best[j] = 3e38f; bpos[j] = 0;
    }
    f2 nx01 = {ntx[0], ntx[1]}, nx23 = {ntx[2], ntx[3]};
    f2 ny01 = {nty[0], nty[1]}, ny23 = {nty[2], nty[3]};
    f2 nz01 = {ntz[0], ntz[1]}, nz23 = {ntz[2], ntz[3]};
    #pragma unroll 4
    for (int c = 0; c < cnt; ++c) {
      float4 cd = tile[c];
      // monotone surrogate |c|^2 - 2 t.c (argmin-equiv to |t-c|^2)
      f2 cx = {cd.x, cd.x}, cy = {cd.y, cd.y};
      f2 cz = {cd.z, cd.z}, cw = {cd.w, cd.w};
      f2 d01 = __builtin_elementwise_fma(nx01, cx, cw);
      d01 = __builtin_elementwise_fma(ny01, cy, d01);
      d01 = __builtin_elementwise_fma(nz01, cz, d01);
      f2 d23 = __builtin_elementwise_fma(nx23, cx, cw);
      d23 = __builtin_elementwise_fma(ny23, cy, d23);
      d23 = __builtin_elementwise_fma(nz23, cz, d23);
      bool l0 = d01.x < best[0]; bpos[0] = l0 ? c : bpos[0]; best[0] = l0 ? d01.x : best[0];
      bool l1 = d01.y < best[1]; bpos[1] = l1 ? c : bpos[1]; best[1] = l1 ? d01.y : best[1];
      bool l2 = d23.x < best[2]; bpos[2] = l2 ? c : bpos[2]; best[2] = l2 ? d23.x : best[2];
      bool l3 = d23.y < best[3]; bpos[3] = l3 ? c : bpos[3]; best[3] = l3 ? d23.y : best[3];
    }
    #pragma unroll
    for (int j = 0; j < 4; ++j) {
      if (act[j]) {
        int p = c0 + bpos[j];
        float4 cd = klist[p];
        float tx = -0.5f * ntx[j], ty = -0.5f * nty[j], tz = -0.5f * ntz[j];
        float dx = tx - cd.x, dy = ty - cd.y, dz = tz - cd.z;
        float dtrue = fmaf(dx, dx, fmaf(dy, dy, dz * dz));  // exact (R1)
        ull pack = ((ull)__float_as_uint(dtrue) << 32) | (unsigned int)kidx[p];
        atomicMin(&tmin[tb + 256 * j], pack);
      }
    }
  } else {
    // ---- forward: kept cands x*1024.. (4/thread) vs target chunk (128) ----
    int t0 = (y - YB) * CHUNK;
    if (x * 1024 >= kc || t0 >= N) return;   // uniform early-exit
    int tcnt = min(CHUNK, N - t0);
    if (tid < tcnt) tile[tid] = ttile[t0 + tid];
    __syncthreads();
    int eb = x * 1024 + tid;
    float ncx[4], ncy[4], ncz[4], c2[4], best[4];
    int bpos[4], li[4];
    bool act[4];
    #pragma unroll
    for (int j = 0; j < 4; ++j) {
      int e = eb + 256 * j;
      act[j] = e < kc;
      float cx = 0.f, cy = 0.f, cz = 0.f;
      c2[j] = 0.f; li[j] = 0;
      if (act[j]) {
        float4 cd = klist[e];
        cx = cd.x; cy = cd.y; cz = cd.z; c2[j] = cd.w;
        li[j] = kidx[e];
      }
      ncx[j] = -2.f * cx; ncy[j] = -2.f * cy; ncz[j] = -2.f * cz;
      best[j] = 3e38f; bpos[j] = 0;
    }
    f2 nx01 = {ncx[0], ncx[1]}, nx23 = {ncx[2], ncx[3]};
    f2 ny01 = {ncy[0], ncy[1]}, ny23 = {ncy[2], ncy[3]};
    f2 nz01 = {ncz[0], ncz[1]}, nz23 = {ncz[2], ncz[3]};
    #pragma unroll 4
    for (int c = 0; c < tcnt; ++c) {
      float4 td = tile[c];
      f2 cx = {td.x, td.x}, cy = {td.y, td.y};
      f2 cz = {td.z, td.z}, cw = {td.w, td.w};
      f2 d01 = __builtin_elementwise_fma(nx01, cx, cw);
      d01 = __builtin_elementwise_fma(ny01, cy, d01);
      d01 = __builtin_elementwise_fma(nz01, cz, d01);
      f2 d23 = __builtin_elementwise_fma(nx23, cx, cw);
      d23 = __builtin_elementwise_fma(ny23, cy, d23);
      d23 = __builtin_elementwise_fma(nz23, cz, d23);
      bool l0 = d01.x < best[0]; bpos[0] = l0 ? c : bpos[0]; best[0] = l0 ? d01.x : best[0];
      bool l1 = d01.y < best[1]; bpos[1] = l1 ? c : bpos[1]; best[1] = l1 ? d01.y : best[1];
      bool l2 = d23.x < best[2]; bpos[2] = l2 ? c : bpos[2]; best[2] = l2 ? d23.x : best[2];
      bool l3 = d23.y < best[3]; bpos[3] = l3 ? c : bpos[3]; best[3] = l3 ? d23.y : best[3];
    }
    #pragma unroll
    for (int j = 0; j < 4; ++j) {
      if (act[j]) {
        float dkey = fmaxf(best[j] + c2[j], 0.f);  // consistent merge key (R3)
        ull pack = ((ull)__float_as_uint(dkey) << 32) |
                   (unsigned int)(t0 + bpos[j]);
        atomicMin(&fmin[li[j]], pack);
      }
    }
  }
}

// ---- Kernel 3: scatter weighted colors into num/den ------------------------
__global__ __launch_bounds__(256) void k_scatter(
    const float* __restrict__ trgb, const ull* __restrict__ tmin,
    float4* __restrict__ numden, int* __restrict__ zerohit,
    float4* __restrict__ zcolor, int N) {
  int t = blockIdx.x * 256 + threadIdx.x;
  if (t >= N) return;
  ull pack = tmin[t];
  float d = __uint_as_float((unsigned int)(pack >> 32));
  int idx = (int)(pack & 0xFFFFFFFFull);
  float r = trgb[3*t], g = trgb[3*t+1], b = trgb[3*t+2];
  if (d == 0.0f) {
    zerohit[idx] = 1;
    zcolor[idx] = make_float4(r, g, b, 0.f);
  } else {
    float w = 1.0f / sqrtf(fmaxf(d, 1e-30f));
    atomicAdd(&numden[idx].x, r * w);
    atomicAdd(&numden[idx].y, g * w);
    atomicAdd(&numden[idx].z, b * w);
    atomicAdd(&numden[idx].w, w);
  }
}

// ---- Kernel 4: final recolor select + L1 reduce ----------------------------
__global__ __launch_bounds__(256) void k_loss(
    const float* __restrict__ crgb, const float* __restrict__ trgb,
    const int* __restrict__ keep, const float4* __restrict__ numden,
    const int* __restrict__ zerohit, const float4* __restrict__ zcolor,
    const ull* __restrict__ fmin, float* __restrict__ out, int L) {
  int l = blockIdx.x * 256 + threadIdx.x;
  float loss = 0.f;
  if (l < L && keep[l]) {
    float rr, rg, rb;
    if (zerohit[l]) {
      float4 z = zcolor[l]; rr = z.x; rg = z.y; rb = z.z;
    } else {
      float4 nd = numden[l];
      if (nd.w != 0.f) { rr = nd.x / nd.w; rg = nd.y / nd.w; rb = nd.z / nd.w; }
      else {
        int ti = (int)(fmin[l] & 0xFFFFFFFFull);
        rr = trgb[3*ti]; rg = trgb[3*ti+1]; rb = trgb[3*ti+2];
      }
    }
    float sr = crgb[3*l]*255.f, sg = crgb[3*l+1]*255.f, sb = crgb[3*l+2]*255.f;
    loss = fabsf(sr - rr) + fabsf(sg - rg) + fabsf(sb - rb);
  }
  for (int o = 32; o > 0; o >>= 1) loss += __shfl_down(loss, o);
  if ((threadIdx.x & 63) == 0) atomicAdd(&out[1], loss);
}

extern "C" void kernel_launch(void* const* d_in, const int* in_sizes, int n_in,
                              void* d_out, int out_size, void* d_ws, size_t ws_size,
                              hipStream_t stream) {
  const float* pred = (const float*)d_in[0];
  const float* cxyz = (const float*)d_in[1];
  const float* crgb = (const float*)d_in[2];
  const float* txyz = (const float*)d_in[3];
  const float* trgb = (const float*)d_in[4];
  const int*   ktgt = (const int*)d_in[5];
  const int*   pnum = (const int*)d_in[6];
  int L = in_sizes[0];
  int N = in_sizes[3] / 3;

  // workspace layout: 16B arrays first, then 8B, 4B, bytes
  char* ws = (char*)d_ws;
  size_t off = 0;
  float4* klist  = (float4*)(ws + off);   off += (size_t)L * 16;
  float4* ttile  = (float4*)(ws + off);   off += (size_t)((N + 3) & ~3) * 16;
  float4* numden = (float4*)(ws + off);   off += (size_t)L * 16;
  float4* zcolor = (float4*)(ws + off);   off += (size_t)L * 16;
  ull* tmin      = (ull*)(ws + off);      off += (size_t)((N + 1) & ~1) * 8;
  ull* fmin      = (ull*)(ws + off);      off += (size_t)L * 8;
  int* keep      = (int*)(ws + off);      off += (size_t)L * 4;
  int* kidx      = (int*)(ws + off);      off += (size_t)L * 4;
  int* zerohit   = (int*)(ws + off);      off += (size_t)L * 4;
  float* thr_slot = (float*)(ws + off);   off += 16;
  int* counters  = (int*)(ws + off);      off += 256;   // [0]=kcount [15]=flag
  unsigned char* islm = (unsigned char*)(ws + off); off += ((size_t)L + 15) & ~15ull;
  float* out = (float*)d_out;

  int nbL = (L + 255) / 256;   // 64
  int nbN = (N + 255) / 256;   // 40
  int mx = max(L, N);

  // Reset the handshake flag (workspace persists across launches; async
  // memset is graph-capture-safe and the only per-launch state we need).
  hipMemsetAsync((void*)(counters + 15), 0, 4, stream);

  // Kernel 1: fused init + keys + select + keep/compact/BCE.
  int IB = (mx + 1023) / 1024;   // 16 init blocks + 1 selector block
  k_init_sel<<<IB + 1, 1024, 0, stream>>>(
      pred, txyz, cxyz, ktgt, pnum, ttile, numden, zerohit, tmin, fmin,
      islm, keep, klist, kidx, counters, out, thr_slot, L, N, IB);

  // Kernel 2: dual-role scan. x covers 1024 outputs/block; y = 128-chunks.
  int gx = (mx + 1023) / 1024;               // 16
  int YB = (L + CHUNK - 1) / CHUNK;          // 128 kept-chunks (exit at kc)
  int YF = (N + CHUNK - 1) / CHUNK;          // 79 target-chunks
  dim3 gs(gx, YB + YF);
  k_scan2<<<gs, SCAN_T, 0, stream>>>(
      txyz, klist, kidx, ttile, counters, tmin, fmin, L, N, YB);

  k_scatter<<<nbN, 256, 0, stream>>>(trgb, tmin, numden, zerohit, zcolor, N);

  k_loss<<<nbL, 256, 0, stream>>>(
      crgb, trgb, keep, numden, zerohit, zcolor, fmin, out, L);
}

// Round 14
// 134.728 us; speedup vs baseline: 1.0421x; 1.0421x over previous
//
#include <hip/hip_runtime.h>
#include <hip/hip_bf16.h>

// Decoder loss: keep-mask (kth-value threshold + local max), BCE coord loss,
// bidirectional NN recolor + L1 rgb loss.
// L=16384 candidates, N=10000 targets, K=8 (collapses to argmin; R1-proven).
// R19 (resubmit x2; R12/R13 benches were broker GPUAcquisitionTimeouts):
// REVERT to R14 (132.1/132.4/132.6, thrice-proven) - final lock.
// R18 resolved the scan diagnostic: packed-FP32 cut VALUBusy 56->41% but
// dur WORSENED 43->49 (VGPR 28->36). With R11 (same direction), the scan is
// LATENCY/SCHEDULE-limited: 43us is a compiler-schedule equilibrium; every
// source deviation (7 tries) perturbs it for the worse. Ideal issue floor
// ~12.5us; the 30us gap is only addressable by full inline-asm (untried,
// high risk). Budget ledger: 132 = 40us harness 256MiB re-poison fill (not
// controllable) + ~43us scan + ~25us small kernels + ~20us launch floor.
// Hard-learned rules for this part:
//   - scan loop: 0.165+-0.005 cyc/pair across SEVEN configs (R8-R18):
//     invariant to VALU count (R11,R18 cut it -> WORSE), LDS ratio,
//     occupancy, split/concurrent, packed-math. Do not touch from HIP.
//   - R15: per-thread grid/shell NN = latency-serialized divergent gather
//     (439us, VALUBusy 0.75%). NEVER pointer-chase NN per-thread here.
//   - scan needs >=128 c-steps per barrier pair (R13: 32-step = 62us) and
//     dual-grid concurrency (R16: serializing bwd/fwd lost 7us).
//   - kernel boundaries ~free (R14); grid.sync ~40us (R4); mass threadfence
//     ~0.1ms (R7). 17-block co-resident release/acquire handshakes OK.
//   - per-chunk surrogate argmin + cross-chunk EXACT-d merge key (R1/R3).
//   - gfx950 VALUBusy uses gfx94x fallback formula - trust duration, not %.

#define SCAN_T 256   // threads per block (scan)
#define CHUNK  128   // tile elements per y-chunk
typedef unsigned long long ull;

// ---- helper: pick bin containing rank from LDS hist (wave 0) ---------------
__device__ __forceinline__ void select_bin(
    unsigned int* hist, int nb, unsigned int rank,
    unsigned int* sB, unsigned int* sR, int tid) {
  if (tid < 64) {
    int g = nb >> 6;
    unsigned int sum = 0;
    for (int j = 0; j < g; ++j) sum += hist[tid * g + j];
    unsigned int incl = sum;
    for (int o = 1; o < 64; o <<= 1) {
      unsigned int v = __shfl_up(incl, o);
      if (tid >= o) incl += v;
    }
    unsigned int excl = incl - sum;
    bool cond = (rank >= excl) && (rank < incl);
    unsigned long long bal = __ballot(cond);
    int first = __ffsll((long long)bal) - 1;
    if (tid == first) {
      unsigned int r = rank - excl, cum = 0;
      for (int j = 0; j < g; ++j) {
        unsigned int c = hist[tid * g + j];
        if (r < cum + c) { *sB = (unsigned int)(tid * g + j); *sR = r - cum; break; }
        cum += c;
      }
    }
  }
}

// ---- Kernel 1: fused init + keys + select + keep/compact/BCE ---------------
// Blocks 0..IB-1: array init, then acquire-spin on counters[15], then the
// old k_keepc role (keep mask, klist compaction, BCE reduce).
// Block IB (selector): monotone keys into LDS + islm, 3-sweep radix select,
// writes thr + zeroes accumulators, release-stores counters[15]=1.
// All IB+1 = 17 blocks co-resident (<= 256 CUs) -> no deadlock; selector
// never waits on init blocks. AGENT-scope atomics for cross-XCD visibility.
__global__ __launch_bounds__(1024) void k_init_sel(
    const float* __restrict__ pred, const float* __restrict__ txyz,
    const float* __restrict__ cxyz, const int* __restrict__ ktgt,
    const int* __restrict__ pnum_p,
    float4* __restrict__ ttile, float4* __restrict__ numden,
    int* __restrict__ zerohit, ull* __restrict__ tmin, ull* __restrict__ fmin,
    unsigned char* __restrict__ islm, int* __restrict__ keep,
    float4* __restrict__ klist, int* __restrict__ kidx,
    int* counters, float* __restrict__ out, float* __restrict__ thr_out,
    int L, int N, int IB) {
  __shared__ unsigned int skey[16384];
  __shared__ unsigned int hist[2048];
  __shared__ unsigned int sB, sR;
  __shared__ float s_thr;
  int tid = threadIdx.x;

  if ((int)blockIdx.x < IB) {
    // ---- init role --------------------------------------------------------
    int gidx = blockIdx.x * 1024 + tid;
    int gsz = IB * 1024;
    for (int i = gidx; i < N; i += gsz) {
      float x = txyz[3*i], y = txyz[3*i+1], z = txyz[3*i+2];
      ttile[i] = make_float4(x, y, z, fmaf(x, x, fmaf(y, y, z * z)));
      tmin[i] = ~0ull;
    }
    for (int i = gidx; i < L; i += gsz) {
      numden[i] = make_float4(0.f, 0.f, 0.f, 0.f);
      zerohit[i] = 0;
      fmin[i] = ~0ull;
    }
    // ---- handshake: wait for selector's thr (release/acquire, AGENT) ------
    if (tid == 0) {
      while (__hip_atomic_load(&counters[15], __ATOMIC_ACQUIRE,
                               __HIP_MEMORY_SCOPE_AGENT) == 0)
        __builtin_amdgcn_s_sleep(8);
      s_thr = thr_out[0];
    }
    __syncthreads();
    float thr = s_thr;
    // ---- keepc role: keep mask + compaction + BCE -------------------------
    // wave = 64 consecutive i -> identical atomicAdd grouping to R12 keepc.
    float term = 0.f;
    for (int i = gidx; i < L; i += gsz) {
      float p = pred[i];
      bool kp = (p > thr) || islm[i];
      keep[i] = kp ? 1 : 0;
      if (kp) {
        int pos = atomicAdd(&counters[0], 1);   // order irrelevant (no ties)
        float x = cxyz[3*i], y = cxyz[3*i+1], z = cxyz[3*i+2];
        klist[pos] = make_float4(x, y, z, fmaf(x, x, fmaf(y, y, z * z)));
        kidx[pos] = i;
      }
      float t = (float)ktgt[i];
      term += fmaxf(p, 0.f) - p * t + log1pf(expf(-fabsf(p)));
    }
    for (int o = 32; o > 0; o >>= 1) term += __shfl_down(term, o);
    if ((tid & 63) == 0) atomicAdd(&out[0], term);
    return;
  }

  // ---- selector role ------------------------------------------------------
  // phase A: monotone keys (LDS) + per-8 local max (global islm)
  int ngroups = L >> 3;
  for (int g = tid; g < ngroups; g += 1024) {
    const float4* pv = (const float4*)pred + (size_t)g * 2;
    float4 a = pv[0], b = pv[1];
    float v[8] = {a.x, a.y, a.z, a.w, b.x, b.y, b.z, b.w};
    int bi = 0; float bv = v[0];
    #pragma unroll
    for (int j = 1; j < 8; ++j) if (v[j] > bv) { bv = v[j]; bi = j; }
    ull lmpack = 0ull;
    #pragma unroll
    for (int j = 0; j < 8; ++j) {
      unsigned int fb = __float_as_uint(v[j]);
      unsigned int mk = (fb & 0x80000000u) ? ~fb : (fb | 0x80000000u);
      if (j == bi) { mk = 0xFF800000u; lmpack |= 1ull << (8 * j); }  // +inf
      skey[g * 8 + j] = mk;
    }
    *(ull*)(islm + (size_t)g * 8) = lmpack;
  }
  __syncthreads();

  // phase B: 3-sweep radix select over LDS keys
  unsigned int rank = (unsigned int)(L - pnum_p[0] - 1);
  const uint4* s4 = (const uint4*)skey;
  int n4 = L >> 2;
  for (int b = tid; b < 2048; b += 1024) hist[b] = 0u;
  __syncthreads();
  for (int i = tid; i < n4; i += 1024) {
    uint4 v = s4[i];
    atomicAdd(&hist[v.x >> 21], 1u); atomicAdd(&hist[v.y >> 21], 1u);
    atomicAdd(&hist[v.z >> 21], 1u); atomicAdd(&hist[v.w >> 21], 1u);
  }
  __syncthreads();
  select_bin(hist, 2048, rank, &sB, &sR, tid);
  __syncthreads();
  unsigned int B1 = sB, R1 = sR;
  for (int b = tid; b < 2048; b += 1024) hist[b] = 0u;
  __syncthreads();
  for (int i = tid; i < n4; i += 1024) {
    uint4 v = s4[i];
    if ((v.x >> 21) == B1) atomicAdd(&hist[(v.x >> 10) & 2047u], 1u);
    if ((v.y >> 21) == B1) atomicAdd(&hist[(v.y >> 10) & 2047u], 1u);
    if ((v.z >> 21) == B1) atomicAdd(&hist[(v.z >> 10) & 2047u], 1u);
    if ((v.w >> 21) == B1) atomicAdd(&hist[(v.w >> 10) & 2047u], 1u);
  }
  __syncthreads();
  select_bin(hist, 2048, R1, &sB, &sR, tid);
  __syncthreads();
  unsigned int B2 = sB, R2 = sR;
  for (int b = tid; b < 1024; b += 1024) hist[b] = 0u;
  __syncthreads();
  unsigned int top22 = (B1 << 11) | B2;
  for (int i = tid; i < n4; i += 1024) {
    uint4 v = s4[i];
    if ((v.x >> 10) == top22) atomicAdd(&hist[v.x & 1023u], 1u);
    if ((v.y >> 10) == top22) atomicAdd(&hist[v.y & 1023u], 1u);
    if ((v.z >> 10) == top22) atomicAdd(&hist[v.z & 1023u], 1u);
    if ((v.w >> 10) == top22) atomicAdd(&hist[v.w & 1023u], 1u);
  }
  __syncthreads();
  select_bin(hist, 1024, R2, &sB, &sR, tid);
  __syncthreads();
  if (tid == 0) {
    unsigned int fkey = (B1 << 21) | (B2 << 10) | sB;
    unsigned int fb = (fkey & 0x80000000u) ? (fkey & 0x7FFFFFFFu) : ~fkey;
    thr_out[0] = __uint_as_float(fb);
    out[0] = 0.f; out[1] = 0.f;       // accumulators zeroed BEFORE release
    #pragma unroll
    for (int c = 0; c < 8; ++c) counters[c] = 0;
  }
  __syncthreads();   // islm + thr + zeroes happen-before the release store
  if (tid == 0)
    __hip_atomic_store(&counters[15], 1, __ATOMIC_RELEASE,
                       __HIP_MEMORY_SCOPE_AGENT);
}

// ---- Kernel 2: dual-role scan (bwd y<YB, fwd y>=YB), LDS-tiled -------------
// R10 body (proven 42-43us): 4 outputs/thread, CHUNK=128, ~1270 active blocks
// (bwd 640 + fwd 632 CONCURRENT - do not split, R16 lost 7us serializing).
__global__ __launch_bounds__(SCAN_T) void k_scan2(
    const float* __restrict__ txyz, const float4* __restrict__ klist,
    const int* __restrict__ kidx, const float4* __restrict__ ttile,
    const int* __restrict__ counters, ull* __restrict__ tmin,
    ull* __restrict__ fmin, int L, int N, int YB) {
  __shared__ float4 tile[CHUNK];
  int tid = threadIdx.x, x = blockIdx.x, y = blockIdx.y;
  int kc = counters[0];

  if (y < YB) {
    // ---- backward: targets x*1024.. (4/thread) vs kept chunk y (128) ------
    int c0 = y * CHUNK;
    if (x * 1024 >= N || c0 >= kc) return;   // uniform early-exit
    int cnt = min(CHUNK, kc - c0);
    if (tid < cnt) tile[tid] = klist[c0 + tid];
    __syncthreads();
    int tb = x * 1024 + tid;
    float ntx[4], nty[4], ntz[4], best[4];
    int bpos[4];
    bool act[4];
    #pragma unroll
    for (int j = 0; j < 4; ++j) {
      int t = tb + 256 * j;
      act[j] = t < N;
      float tx = 0.f, ty = 0.f, tz = 0.f;
      if (act[j]) { tx = txyz[3*t]; ty = txyz[3*t+1]; tz = txyz[3*t+2]; }
      ntx[j] = -2.f * tx; nty[j] = -2.f * ty; ntz[j] = -2.f * tz;
      best[j] = 3e38f; bpos[j] = 0;
    }
    #pragma unroll 4
    for (int c = 0; c < cnt; ++c) {
      float4 cd = tile[c];
      #pragma unroll
      for (int j = 0; j < 4; ++j) {
        // monotone surrogate |c|^2 - 2 t.c (argmin-equiv to |t-c|^2)
        float d = fmaf(ntx[j], cd.x, cd.w);
        d = fmaf(nty[j], cd.y, d);
        d = fmaf(ntz[j], cd.z, d);
        if (d < best[j]) { best[j] = d; bpos[j] = c; }
      }
    }
    #pragma unroll
    for (int j = 0; j < 4; ++j) {
      if (act[j]) {
        int p = c0 + bpos[j];
        float4 cd = klist[p];
        float tx = -0.5f * ntx[j], ty = -0.5f * nty[j], tz = -0.5f * ntz[j];
        float dx = tx - cd.x, dy = ty - cd.y, dz = tz - cd.z;
        float dtrue = fmaf(dx, dx, fmaf(dy, dy, dz * dz));  // exact (R1)
        ull pack = ((ull)__float_as_uint(dtrue) << 32) | (unsigned int)kidx[p];
        atomicMin(&tmin[tb + 256 * j], pack);
      }
    }
  } else {
    // ---- forward: kept cands x*1024.. (4/thread) vs target chunk (128) ----
    int t0 = (y - YB) * CHUNK;
    if (x * 1024 >= kc || t0 >= N) return;   // uniform early-exit
    int tcnt = min(CHUNK, N - t0);
    if (tid < tcnt) tile[tid] = ttile[t0 + tid];
    __syncthreads();
    int eb = x * 1024 + tid;
    float ncx[4], ncy[4], ncz[4], c2[4], best[4];
    int bpos[4], li[4];
    bool act[4];
    #pragma unroll
    for (int j = 0; j < 4; ++j) {
      int e = eb + 256 * j;
      act[j] = e < kc;
      float cx = 0.f, cy = 0.f, cz = 0.f;
      c2[j] = 0.f; li[j] = 0;
      if (act[j]) {
        float4 cd = klist[e];
        cx = cd.x; cy = cd.y; cz = cd.z; c2[j] = cd.w;
        li[j] = kidx[e];
      }
      ncx[j] = -2.f * cx; ncy[j] = -2.f * cy; ncz[j] = -2.f * cz;
      best[j] = 3e38f; bpos[j] = 0;
    }
    #pragma unroll 4
    for (int c = 0; c < tcnt; ++c) {
      float4 td = tile[c];
      #pragma unroll
      for (int j = 0; j < 4; ++j) {
        float d = fmaf(ncx[j], td.x, td.w);
        d = fmaf(ncy[j], td.y, d);
        d = fmaf(ncz[j], td.z, d);
        if (d < best[j]) { best[j] = d; bpos[j] = c; }
      }
    }
    #pragma unroll
    for (int j = 0; j < 4; ++j) {
      if (act[j]) {
        float dkey = fmaxf(best[j] + c2[j], 0.f);  // consistent merge key (R3)
        ull pack = ((ull)__float_as_uint(dkey) << 32) |
                   (unsigned int)(t0 + bpos[j]);
        atomicMin(&fmin[li[j]], pack);
      }
    }
  }
}

// ---- Kernel 3: scatter weighted colors into num/den ------------------------
__global__ __launch_bounds__(256) void k_scatter(
    const float* __restrict__ trgb, const ull* __restrict__ tmin,
    float4* __restrict__ numden, int* __restrict__ zerohit,
    float4* __restrict__ zcolor, int N) {
  int t = blockIdx.x * 256 + threadIdx.x;
  if (t >= N) return;
  ull pack = tmin[t];
  float d = __uint_as_float((unsigned int)(pack >> 32));
  int idx = (int)(pack & 0xFFFFFFFFull);
  float r = trgb[3*t], g = trgb[3*t+1], b = trgb[3*t+2];
  if (d == 0.0f) {
    zerohit[idx] = 1;
    zcolor[idx] = make_float4(r, g, b, 0.f);
  } else {
    float w = 1.0f / sqrtf(fmaxf(d, 1e-30f));
    atomicAdd(&numden[idx].x, r * w);
    atomicAdd(&numden[idx].y, g * w);
    atomicAdd(&numden[idx].z, b * w);
    atomicAdd(&numden[idx].w, w);
  }
}

// ---- Kernel 4: final recolor select + L1 reduce ----------------------------
__global__ __launch_bounds__(256) void k_loss(
    const float* __restrict__ crgb, const float* __restrict__ trgb,
    const int* __restrict__ keep, const float4* __restrict__ numden,
    const int* __restrict__ zerohit, const float4* __restrict__ zcolor,
    const ull* __restrict__ fmin, float* __restrict__ out, int L) {
  int l = blockIdx.x * 256 + threadIdx.x;
  float loss = 0.f;
  if (l < L && keep[l]) {
    float rr, rg, rb;
    if (zerohit[l]) {
      float4 z = zcolor[l]; rr = z.x; rg = z.y; rb = z.z;
    } else {
      float4 nd = numden[l];
      if (nd.w != 0.f) { rr = nd.x / nd.w; rg = nd.y / nd.w; rb = nd.z / nd.w; }
      else {
        int ti = (int)(fmin[l] & 0xFFFFFFFFull);
        rr = trgb[3*ti]; rg = trgb[3*ti+1]; rb = trgb[3*ti+2];
      }
    }
    float sr = crgb[3*l]*255.f, sg = crgb[3*l+1]*255.f, sb = crgb[3*l+2]*255.f;
    loss = fabsf(sr - rr) + fabsf(sg - rg) + fabsf(sb - rb);
  }
  for (int o = 32; o > 0; o >>= 1) loss += __shfl_down(loss, o);
  if ((threadIdx.x & 63) == 0) atomicAdd(&out[1], loss);
}

extern "C" void kernel_launch(void* const* d_in, const int* in_sizes, int n_in,
                              void* d_out, int out_size, void* d_ws, size_t ws_size,
                              hipStream_t stream) {
  const float* pred = (const float*)d_in[0];
  const float* cxyz = (const float*)d_in[1];
  const float* crgb = (const float*)d_in[2];
  const float* txyz = (const float*)d_in[3];
  const float* trgb = (const float*)d_in[4];
  const int*   ktgt = (const int*)d_in[5];
  const int*   pnum = (const int*)d_in[6];
  int L = in_sizes[0];
  int N = in_sizes[3] / 3;

  // workspace layout: 16B arrays first, then 8B, 4B, bytes
  char* ws = (char*)d_ws;
  size_t off = 0;
  float4* klist  = (float4*)(ws + off);   off += (size_t)L * 16;
  float4* ttile  = (float4*)(ws + off);   off += (size_t)((N + 3) & ~3) * 16;
  float4* numden = (float4*)(ws + off);   off += (size_t)L * 16;
  float4* zcolor = (float4*)(ws + off);   off += (size_t)L * 16;
  ull* tmin      = (ull*)(ws + off);      off += (size_t)((N + 1) & ~1) * 8;
  ull* fmin      = (ull*)(ws + off);      off += (size_t)L * 8;
  int* keep      = (int*)(ws + off);      off += (size_t)L * 4;
  int* kidx      = (int*)(ws + off);      off += (size_t)L * 4;
  int* zerohit   = (int*)(ws + off);      off += (size_t)L * 4;
  float* thr_slot = (float*)(ws + off);   off += 16;
  int* counters  = (int*)(ws + off);      off += 256;   // [0]=kcount [15]=flag
  unsigned char* islm = (unsigned char*)(ws + off); off += ((size_t)L + 15) & ~15ull;
  float* out = (float*)d_out;

  int nbL = (L + 255) / 256;   // 64
  int nbN = (N + 255) / 256;   // 40
  int mx = max(L, N);

  // Reset the handshake flag (workspace persists across launches; async
  // memset is graph-capture-safe and the only per-launch state we need).
  hipMemsetAsync((void*)(counters + 15), 0, 4, stream);

  // Kernel 1: fused init + keys + select + keep/compact/BCE.
  int IB = (mx + 1023) / 1024;   // 16 init blocks + 1 selector block
  k_init_sel<<<IB + 1, 1024, 0, stream>>>(
      pred, txyz, cxyz, ktgt, pnum, ttile, numden, zerohit, tmin, fmin,
      islm, keep, klist, kidx, counters, out, thr_slot, L, N, IB);

  // Kernel 2: dual-role scan. x covers 1024 outputs/block; y = 128-chunks.
  int gx = (mx + 1023) / 1024;               // 16
  int YB = (L + CHUNK - 1) / CHUNK;          // 128 kept-chunks (exit at kc)
  int YF = (N + CHUNK - 1) / CHUNK;          // 79 target-chunks
  dim3 gs(gx, YB + YF);
  k_scan2<<<gs, SCAN_T, 0, stream>>>(
      txyz, klist, kidx, ttile, counters, tmin, fmin, L, N, YB);

  k_scatter<<<nbN, 256, 0, stream>>>(trgb, tmin, numden, zerohit, zcolor, N);

  k_loss<<<nbL, 256, 0, stream>>>(
      crgb, trgb, keep, numden, zerohit, zcolor, fmin, out, L);
}